// Round 4
// baseline (1455.286 us; speedup 1.0000x reference)
//
#include <hip/hip_runtime.h>
#include <cstdint>
#include <cstddef>

// ---------------------------------------------------------------------------
// Fused GQA attention block for MI355X (gfx950).
// B=4 T=1024 D=4096 N=32 Kh=8 G=4 H=128, rotary=80, theta=1e6, eps=1e-6.
// Pipeline: [transpose+cvt weights/x -> bf16] -> GEMM(qkv) -> norm/rope/gate
//           + V transpose -> flash attention (causal) -> GEMM(out proj).
// R5: uniform 8-phase GEMM schedule (m201-faithful). 2 K-tiles/iter, 2 LDS
// buffers (128 KiB). Every phase: {<=8 ds_reads for a FUTURE phase || 1
// half-tile stage (2 gload_lds) -> barrier -> counted lgkm -> 16 MFMA ->
// barrier}. Reads pipelined one phase ahead (A-qm0 of kt read in previous
// block's last phase); per-phase read load 8/8/0/8 so the LDS port (~500-640
// cyc/phase) stays under the MFMA shadow (620 cyc/phase).
// Staging: 1 half/phase, A-halves first. Gates (counted, never 0 mid-loop):
//   vmcnt(4) @P2/P6-end: forces both A-halves of the next kt (B-halves fly)
//   vmcnt(2) @P3/P7-end: forces both B-halves (next Ah0 flies)
// No-overwrite proof: a buffer's halves are staged only in phases after the
// phase whose lgkmcnt(0)+closing-barrier forced ALL ds_reads of the buffer's
// previous occupant (buf0 reads forced by P2's lgkm; buf0 staged P3-P6;
// buf1 reads forced by P6's lgkm; buf1 staged P7,P0',P1',P2').
// Swizzle: chunk ^= (row&7) on 128-B rows (R1/R4-verified 0 conflicts).
// MFMA layouts (guide-verified, 16x16x32 bf16):
//   A-frag: A[m=lane&15][k=(lane>>4)*8+j]
//   B-frag: B[k=(lane>>4)*8+j][n=lane&15]  (from B^T rows)
//   C/D   : row=(lane>>4)*4+r, col=lane&15
// ---------------------------------------------------------------------------

typedef __attribute__((ext_vector_type(8))) short short8;
typedef __attribute__((ext_vector_type(4))) float float4v;

__device__ __forceinline__ unsigned short f2bf(float f) {
  unsigned u = __builtin_bit_cast(unsigned, f);
  u += 0x7fffu + ((u >> 16) & 1u);            // RNE
  return (unsigned short)(u >> 16);
}
__device__ __forceinline__ float bf2f(unsigned short h) {
  unsigned u = ((unsigned)h) << 16;
  return __builtin_bit_cast(float, u);
}

// async global->LDS, 16B per lane. LDS dest is wave-uniform base + lane*16.
__device__ __forceinline__ void gload_lds16(const void* g, void* l) {
  typedef const __attribute__((address_space(1))) void as1_cv;
  typedef __attribute__((address_space(3))) void as3_v;
  __builtin_amdgcn_global_load_lds((as1_cv*)g, (as3_v*)l, 16, 0, 0);
}

// ---------------------------------------------------------------------------
// Transpose + f32->bf16 convert: dst[c][r] = bf16(src[r][c]); src is (R, C).
// ---------------------------------------------------------------------------
__global__ __launch_bounds__(256) void transpose_cvt(
    const float* __restrict__ src, unsigned short* __restrict__ dst,
    int R, int C) {
  __shared__ float tile[32][33];
  const int c0 = blockIdx.x * 32, r0 = blockIdx.y * 32;
  for (int i = threadIdx.y; i < 32; i += 8)
    tile[i][threadIdx.x] = src[(size_t)(r0 + i) * C + c0 + threadIdx.x];
  __syncthreads();
  for (int i = threadIdx.y; i < 32; i += 8)
    dst[(size_t)(c0 + i) * R + r0 + threadIdx.x] = f2bf(tile[threadIdx.x][i]);
}

__global__ __launch_bounds__(256) void cvt_f32_bf16(
    const float* __restrict__ src, unsigned short* __restrict__ dst, int n4) {
  int i = blockIdx.x * blockDim.x + threadIdx.x;
  if (i >= n4) return;
  float4 f = ((const float4*)src)[i];
  ushort4 o;
  o.x = f2bf(f.x); o.y = f2bf(f.y); o.z = f2bf(f.z); o.w = f2bf(f.w);
  ((ushort4*)dst)[i] = o;
}

// bf16 64x64-tile transpose for V: qkv cols [9216+kh*128, +128) -> vt (b,kh,h,t).
// grid (16 t-tiles, 2 h-tiles, 32 b*kh), block 256.
__global__ __launch_bounds__(256) void v_transpose(
    const unsigned short* __restrict__ qkv, unsigned short* __restrict__ vtb) {
  __shared__ unsigned short tile[64][65];
  const int t0 = blockIdx.x * 64, h0 = blockIdx.y * 64;
  const int bk = blockIdx.z, b = bk >> 3, kh = bk & 7;
  const int tx = threadIdx.x & 63, ty = threadIdx.x >> 6;
  const unsigned short* src =
      qkv + (size_t)(b * 1024 + t0) * 10240 + 9216 + kh * 128 + h0;
  for (int i = ty; i < 64; i += 4)
    tile[i][tx] = src[(size_t)i * 10240 + tx];
  __syncthreads();
  unsigned short* dst = vtb + ((size_t)bk * 128 + h0) * 1024 + t0;
  for (int i = ty; i < 64; i += 4)
    dst[(size_t)i * 1024 + tx] = tile[tx][i];
}

// ---------------------------------------------------------------------------
// GEMM: C(M,N) = A(M,Kd) * BT(N,Kd)^T, bf16 in, f32 acc.
// 256x256 tile, BK=64, 512 threads = 8 waves (2x4), per-wave C = 128x64.
// LDS: 2 buffers x (A 256x64 + B 256x64) bf16 = 128 KiB; halves = 128 rows.
// Iteration = 2 K-tiles (kt0 even->buf0, kt1 odd->buf1), 8 phases.
//   reads/phase (all for a LATER phase): P0:B01(kt0) P1:A1(kt0) P2:-
//     P3:A0(kt1) P4:B01(kt1) P5:A1(kt1) P6:- P7:A0(kt0')
//   stage/phase: P0:Ah1(kt1) P1:Bh0(kt1) P2:Bh1(kt1) P3:Ah0(kt2) P4:Ah1(kt2)
//     P5:Bh0(kt2) P6:Bh1(kt2) P7:Ah0(kt3)
//   lgkm: P0:4 P1:8 P2:0 P3:8 P4:4 P5:8 P6:0 P7:8
//   vmcnt gates: P2:4 P3:2 (0 on last iter) P6:4 P7:2
// ---------------------------------------------------------------------------
template <bool BF16OUT>
__global__ __launch_bounds__(512, 2) void gemm_bt256(
    const unsigned short* __restrict__ A, const unsigned short* __restrict__ BT,
    void* __restrict__ Cv, int M, int N, int Kd) {
  __shared__ unsigned short As[2][16384];   // 256 rows x 64 (bf16)
  __shared__ unsigned short Bs[2][16384];

  const int tid = threadIdx.x;
  const int lane = tid & 63;
  const int wv = tid >> 6;
  const int wr = wv >> 2, wc = wv & 3;       // 2 x 4 wave grid
  const int m0 = blockIdx.y * 256, n0 = blockIdx.x * 256;
  const int ml = lane & 15, q = lane >> 4;

  // staging: row = tid>>3 (0..63) within a 64-row group; phys chunk = tid&7;
  // source chunk = phys ^ (row&7) (row&7 invariant across +64/+128 shifts).
  const int srow = tid >> 3;
  const int sgc = ((tid & 7) ^ (srow & 7)) * 8;
  const unsigned short* gAs = A + (size_t)(m0 + srow) * Kd + sgc;
  const unsigned short* gBs = BT + (size_t)(n0 + srow) * Kd + sgc;
  const size_t r64K = (size_t)64 * Kd, r128K = (size_t)128 * Kd;
  const int ls = tid * 8;

  // fragment reads (frag row bases %16==0 -> row&7 == ml&7)
  const int rch = (q ^ (ml & 7)) * 8;        // ks=0 chunk; ks=1 -> ^32
  const int aBase = (wr * 128 + ml) * 64 + rch;
  const int bBase = (wc * 64 + ml) * 64 + rch;

  float4v acc[8][4];
#pragma unroll
  for (int i = 0; i < 8; ++i)
#pragma unroll
    for (int j = 0; j < 4; ++j) acc[i][j] = (float4v)0.0f;

  const int NI = Kd >> 7;                    // iterations (2 K-tiles each)

  short8 af0[8], af1[8], b0[4], b1[4];

#define STG_A(bf, h, col) do {                                            \
    gload_lds16(gAs + (size_t)(h) * r128K + (col), &As[bf][(h)*8192 + ls]); \
    gload_lds16(gAs + (size_t)(h) * r128K + r64K + (col),                  \
                &As[bf][(h)*8192 + 4096 + ls]);                            \
  } while (0)
#define STG_B(bf, h, col) do {                                            \
    gload_lds16(gBs + (size_t)(h) * r128K + (col), &Bs[bf][(h)*8192 + ls]); \
    gload_lds16(gBs + (size_t)(h) * r128K + r64K + (col),                  \
                &Bs[bf][(h)*8192 + 4096 + ls]);                            \
  } while (0)
#define READ_AF(DST, BUFP, QM) do {                                       \
    _Pragma("unroll")                                                     \
    for (int ii = 0; ii < 4; ++ii) {                                      \
      DST[ii*2]   = *(const short8*)&(BUFP)[aBase + (QM)*4096 + ii*1024]; \
      DST[ii*2+1] = *(const short8*)&(BUFP)[(aBase + (QM)*4096 + ii*1024) ^ 32]; \
    } } while (0)
#define READ_BF(DST, BUFP, QN) do {                                       \
    _Pragma("unroll")                                                     \
    for (int jj = 0; jj < 2; ++jj) {                                      \
      DST[jj*2]   = *(const short8*)&(BUFP)[bBase + (QN)*2048 + jj*1024]; \
      DST[jj*2+1] = *(const short8*)&(BUFP)[(bBase + (QN)*2048 + jj*1024) ^ 32]; \
    } } while (0)
#define MFMA_Q(AF, BF, R0, C0) do {                                       \
    _Pragma("unroll")                                                     \
    for (int ks = 0; ks < 2; ++ks)                                        \
      _Pragma("unroll")                                                   \
      for (int ii = 0; ii < 4; ++ii)                                      \
        _Pragma("unroll")                                                 \
        for (int jj = 0; jj < 2; ++jj)                                    \
          acc[(R0)+ii][(C0)+jj] = __builtin_amdgcn_mfma_f32_16x16x32_bf16( \
              AF[ii*2+ks], BF[jj*2+ks], acc[(R0)+ii][(C0)+jj], 0, 0, 0);  \
  } while (0)
#define PH_MID(NLG) do {                                                  \
    __builtin_amdgcn_sched_barrier(0);                                    \
    __builtin_amdgcn_s_barrier();                                         \
    asm volatile("s_waitcnt lgkmcnt(" #NLG ")" ::: "memory");             \
    __builtin_amdgcn_sched_barrier(0);                                    \
    __builtin_amdgcn_s_setprio(1);                                        \
  } while (0)
#define PH_END() do {                                                     \
    __builtin_amdgcn_s_setprio(0);                                        \
    __builtin_amdgcn_s_barrier();                                         \
  } while (0)

  // prologue: buf0 fully staged + buf1.Ah0 flying; pre-read A0(kt0).
  STG_A(0, 0, 0); STG_A(0, 1, 0); STG_B(0, 0, 0); STG_B(0, 1, 0);
  STG_A(1, 0, 64);
  asm volatile("s_waitcnt vmcnt(2)" ::: "memory");
  __builtin_amdgcn_s_barrier();
  READ_AF(af0, As[0], 0);

  for (int i = 0; i < NI; ++i) {
    const int c1 = i * 128 + 64, c2 = i * 128 + 128, c3 = i * 128 + 192;
    const bool more = (i + 1 < NI);

    // P0: MFMA Q(0,0) kt0
    READ_BF(b0, Bs[0], 0); READ_BF(b1, Bs[0], 1);
    STG_A(1, 1, c1);
    PH_MID(4);                       // forces af0 + b0 (b1 flies)
    MFMA_Q(af0, b0, 0, 0);
    PH_END();

    // P1: MFMA Q(0,1) kt0
    READ_AF(af1, As[0], 1);
    STG_B(1, 0, c1);
    PH_MID(8);                       // forces b1 (af1 flies)
    MFMA_Q(af0, b1, 0, 2);
    PH_END();

    // P2: MFMA Q(1,0) kt0; gate A-halves(kt1)
    STG_B(1, 1, c1);
    asm volatile("s_waitcnt vmcnt(4)" ::: "memory");
    PH_MID(0);                       // forces af1
    MFMA_Q(af1, b0, 4, 0);
    PH_END();

    // P3: MFMA Q(1,1) kt0; gate B-halves(kt1)
    READ_AF(af0, As[1], 0);
    if (more) {
      STG_A(0, 0, c2);
      asm volatile("s_waitcnt vmcnt(2)" ::: "memory");
    } else {
      asm volatile("s_waitcnt vmcnt(0)" ::: "memory");
    }
    PH_MID(8);                       // af0 flies
    MFMA_Q(af1, b1, 4, 2);
    PH_END();

    // P4: MFMA Q(0,0) kt1
    READ_BF(b0, Bs[1], 0); READ_BF(b1, Bs[1], 1);
    if (more) STG_A(0, 1, c2);
    PH_MID(4);                       // forces af0 + b0
    MFMA_Q(af0, b0, 0, 0);
    PH_END();

    // P5: MFMA Q(0,1) kt1
    READ_AF(af1, As[1], 1);
    if (more) STG_B(0, 0, c2);
    PH_MID(8);                       // forces b1
    MFMA_Q(af0, b1, 0, 2);
    PH_END();

    // P6: MFMA Q(1,0) kt1; gate A-halves(kt2)
    if (more) STG_B(0, 1, c2);
    asm volatile("s_waitcnt vmcnt(4)" ::: "memory");
    PH_MID(0);                       // forces af1
    MFMA_Q(af1, b0, 4, 0);
    PH_END();

    // P7: MFMA Q(1,1) kt1; gate B-halves(kt2)
    if (more) {
      READ_AF(af0, As[0], 0);
      STG_A(1, 0, c3);
    }
    asm volatile("s_waitcnt vmcnt(2)" ::: "memory");
    PH_MID(8);
    MFMA_Q(af1, b1, 4, 2);
    PH_END();
  }

#undef STG_A
#undef STG_B
#undef READ_AF
#undef READ_BF
#undef MFMA_Q
#undef PH_MID
#undef PH_END

  // epilogue (acc[i][j]: rows wr*128+i*16+q*4, cols wc*64+j*16+ml)
#pragma unroll
  for (int i = 0; i < 8; ++i) {
#pragma unroll
    for (int j = 0; j < 4; ++j) {
      const int grow = m0 + wr * 128 + i * 16 + q * 4;
      const int gcol = n0 + wc * 64 + j * 16 + ml;
#pragma unroll
      for (int r = 0; r < 4; ++r) {
        size_t idx = (size_t)(grow + r) * N + gcol;
        if constexpr (BF16OUT)
          ((unsigned short*)Cv)[idx] = f2bf(acc[i][j][r]);
        else
          ((float*)Cv)[idx] = acc[i][j][r];
      }
    }
  }
}

// ---------------------------------------------------------------------------
// Postprocess q/gate/k (V handled by v_transpose):
//   hs<32 : q head hs  -> rmsnorm, rope -> q_rot; gate -> sigmoid -> sgb
//   hs>=32: k head     -> rmsnorm, rope -> k_rot  (layout (b,kh,t,h))
// One wave per (row m, slot hs in 0..39). grid 40960, block 256.
// ---------------------------------------------------------------------------
__global__ __launch_bounds__(256) void postproc_kernel(
    const unsigned short* __restrict__ qkv, const int* __restrict__ positions,
    const float* __restrict__ qnw, const float* __restrict__ knw,
    unsigned short* __restrict__ q_rot, unsigned short* __restrict__ sgb,
    unsigned short* __restrict__ k_rot) {
  const int wave = threadIdx.x >> 6, lane = threadIdx.x & 63;
  const int gslot = blockIdx.x * 4 + wave;
  const int m = gslot / 40, hs = gslot % 40;
  const int b = m >> 10, t = m & 1023;

  const unsigned short* base = (hs < 32)
      ? qkv + (size_t)m * 10240 + hs * 256
      : qkv + (size_t)m * 10240 + 8192 + (hs - 32) * 128;

  float v1 = bf2f(base[lane]);        // h = lane
  float v2 = bf2f(base[64 + lane]);   // h = lane + 64

  // RMS norm over 128 (1+w applied before rope; rope mixes channels)
  float ss = v1 * v1 + v2 * v2;
  for (int off = 32; off > 0; off >>= 1) ss += __shfl_xor(ss, off);
  const float r = rsqrtf(ss * (1.0f / 128.0f) + 1e-6f);
  const float* nw = (hs < 32) ? qnw : knw;
  v1 *= r * (1.0f + nw[lane]);
  v2 *= r * (1.0f + nw[64 + lane]);

  // RoPE dims 0..79: pair (i, i+40). ln(1e6)/40 = 0.34538776...
  const float pos = (float)positions[m];
  const int i1 = (lane < 40) ? lane : lane - 40;
  const float ang1 = pos * expf(-0.3453877639491068f * (float)i1);
  const float s1 = sinf(ang1), c1 = cosf(ang1);
  const float ang2 = pos * expf(-0.3453877639491068f * (float)(lane + 24));
  const float s2 = sinf(ang2), c2 = cosf(ang2);

  const float shA1 = __shfl(v1, (lane + 40) & 63);
  const float shA2 = __shfl(v2, (lane + 40) & 63);
  const float shX = __shfl(v1, (lane + 24) & 63);
  const float pA = (lane < 24) ? shA1 : shA2;  // x[lane+40]
  const float o1 = (lane < 40) ? (v1 * c1 - pA * s1) : (v1 * c1 + shX * s1);
  const float o2 = (lane < 16) ? (v2 * c2 + shX * s2) : v2;

  if (hs < 32) {
    size_t qb = ((size_t)m * 32 + hs) * 128;
    q_rot[qb + lane] = f2bf(o1);
    q_rot[qb + 64 + lane] = f2bf(o2);
    float g1 = bf2f(base[128 + lane]), g2 = bf2f(base[192 + lane]);
    sgb[qb + lane] = f2bf(1.0f / (1.0f + expf(-g1)));
    sgb[qb + 64 + lane] = f2bf(1.0f / (1.0f + expf(-g2)));
  } else {
    const int kh = hs - 32;
    size_t kb = ((size_t)(b * 8 + kh) * 1024 + t) * 128;
    k_rot[kb + lane] = f2bf(o1);
    k_rot[kb + 64 + lane] = f2bf(o2);
  }
}

// ---------------------------------------------------------------------------
// Flash attention. Block = (b, n, 64-row Q tile). 4 waves x 16 q-rows.
// Ks/Vts XOR-swizzled; Ps padded to stride 72. LDS = 16K+16K+9K = 41KB.
// ---------------------------------------------------------------------------
__global__ __launch_bounds__(256) void attn_kernel(
    const unsigned short* __restrict__ q_rot, const unsigned short* __restrict__ k_rot,
    const unsigned short* __restrict__ vt, const unsigned short* __restrict__ sgate,
    unsigned short* __restrict__ attn_out) {
  __shared__ unsigned short Ks[64 * 128];   // 16 chunks/row, swizzle mask 15
  __shared__ unsigned short Vts[128 * 64];  // 8 chunks/row, swizzle mask 7
  __shared__ unsigned short Ps[64 * 72];    // padded, plain stores

  const int tid = threadIdx.x;
  const int lane = tid & 63, w = tid >> 6;
  const int qt = blockIdx.x & 15;
  const int n = (blockIdx.x >> 4) & 31;
  const int b = blockIdx.x >> 9;
  const int kh = n >> 2;
  const int t0 = qt * 64;
  const int ml = lane & 15, q = lane >> 4;
  const float SCALE = 0.08838834764831845f;  // H^-0.5

  short8 aq[4];
  {
    const unsigned short* qp =
        q_rot + (((size_t)(b * 1024 + t0 + w * 16 + ml)) * 32 + n) * 128 + q * 8;
#pragma unroll
    for (int ks = 0; ks < 4; ++ks) aq[ks] = *(const short8*)(qp + ks * 32);
  }

  float4v O[8];
#pragma unroll
  for (int i = 0; i < 8; ++i) O[i] = (float4v)0.0f;
  float mrow[4] = {-3e38f, -3e38f, -3e38f, -3e38f};
  float lrow[4] = {0.f, 0.f, 0.f, 0.f};

  const unsigned short* kbase = k_rot + (size_t)(b * 8 + kh) * 1024 * 128;
  const unsigned short* vbase = vt + (size_t)(b * 8 + kh) * 128 * 1024;
  const int rK = tid >> 4, cK = tid & 15;  // K stage: 64 rows x 16 chunks
  const int cKsw = (cK ^ rK) * 8;          // rK&15 == rK
  const int rV = tid >> 3, cV = tid & 7;   // V stage: 128 rows x 8 chunks
  const int cVsw = (cV ^ (rV & 7)) * 8;

  for (int si = 0; si <= qt; ++si) {
    const int s0 = si * 64;
#pragma unroll
    for (int it = 0; it < 4; ++it) {
      const int li = it * 256 + tid;
      gload_lds16(kbase + (size_t)(s0 + rK + it * 16) * 128 + cKsw, &Ks[li * 8]);
      gload_lds16(vbase + (size_t)(rV + it * 32) * 1024 + s0 + cVsw, &Vts[li * 8]);
    }
    __syncthreads();

    // S = Q K^T
    float4v Sv[4];
#pragma unroll
    for (int j = 0; j < 4; ++j) Sv[j] = (float4v)0.0f;
#pragma unroll
    for (int ks = 0; ks < 4; ++ks) {
#pragma unroll
      for (int j = 0; j < 4; ++j) {
        short8 bk = *(const short8*)&Ks[(j * 16 + ml) * 128 + (((ks * 4 + q) ^ ml) * 8)];
        Sv[j] = __builtin_amdgcn_mfma_f32_16x16x32_bf16(aq[ks], bk, Sv[j], 0, 0, 0);
      }
    }

    // scale + causal mask + online softmax (rows: t = t0+w*16+q*4+rr)
    float P[4][4];
#pragma unroll
    for (int rr = 0; rr < 4; ++rr) {
      const int tg = t0 + w * 16 + q * 4 + rr;
      float vmax = -3e38f;
#pragma unroll
      for (int j = 0; j < 4; ++j) {
        const int sj = s0 + j * 16 + ml;
        float v = Sv[j][rr] * SCALE;
        if (sj > tg) v = -3.0e38f;
        P[j][rr] = v;
        vmax = fmaxf(vmax, v);
      }
      for (int off = 1; off < 16; off <<= 1) vmax = fmaxf(vmax, __shfl_xor(vmax, off));
      const float mnew = fmaxf(mrow[rr], vmax);
      const float alpha = __expf(mrow[rr] - mnew);
      mrow[rr] = mnew;
      lrow[rr] *= alpha;
#pragma unroll
      for (int ht = 0; ht < 8; ++ht) O[ht][rr] *= alpha;
      float rsum = 0.f;
#pragma unroll
      for (int j = 0; j < 4; ++j) {
        float e = __expf(P[j][rr] - mnew);
        P[j][rr] = e;
        rsum += e;
      }
      for (int off = 1; off < 16; off <<= 1) rsum += __shfl_xor(rsum, off);
      lrow[rr] += rsum;
    }

    // P: C-layout regs -> LDS [t][s] (padded stride 72)
#pragma unroll
    for (int rr = 0; rr < 4; ++rr)
#pragma unroll
      for (int j = 0; j < 4; ++j)
        Ps[(w * 16 + q * 4 + rr) * 72 + j * 16 + ml] = f2bf(P[j][rr]);

    // O += P V
#pragma unroll
    for (int ks = 0; ks < 2; ++ks) {
      short8 ap = *(const short8*)&Ps[(w * 16 + ml) * 72 + ks * 32 + q * 8];
#pragma unroll
      for (int ht = 0; ht < 8; ++ht) {
        short8 bv = *(const short8*)&Vts[(ht * 16 + ml) * 64 + (((ks * 4 + q) ^ (ml & 7)) * 8)];
        O[ht] = __builtin_amdgcn_mfma_f32_16x16x32_bf16(ap, bv, O[ht], 0, 0, 0);
      }
    }
    __syncthreads();
  }

  // epilogue: normalize, gate, store bf16 (M, N*H)
#pragma unroll
  for (int rr = 0; rr < 4; ++rr) {
    const int tg = t0 + w * 16 + q * 4 + rr;
    const size_t ob = ((size_t)(b * 1024 + tg) * 32 + n) * 128;
    const float inv = 1.0f / lrow[rr];
#pragma unroll
    for (int ht = 0; ht < 8; ++ht) {
      const int h = ht * 16 + ml;
      attn_out[ob + h] = f2bf(O[ht][rr] * inv * bf2f(sgate[ob + h]));
    }
  }
}

// ---------------------------------------------------------------------------
extern "C" void kernel_launch(void* const* d_in, const int* in_sizes, int n_in,
                              void* d_out, int out_size, void* d_ws, size_t ws_size,
                              hipStream_t stream) {
  (void)in_sizes; (void)n_in; (void)out_size; (void)ws_size;
  const float* x = (const float*)d_in[0];
  const int* pos = (const int*)d_in[1];
  const float* wq = (const float*)d_in[2];
  const float* wk = (const float*)d_in[3];
  const float* wv = (const float*)d_in[4];
  const float* wo = (const float*)d_in[5];
  const float* qnw = (const float*)d_in[6];
  const float* knw = (const float*)d_in[7];
  float* out = (float*)d_out;

  unsigned short* ws = (unsigned short*)d_ws;
  unsigned short* x_bf = ws;                         // 16777216
  unsigned short* wT = x_bf + 16777216;              // 41943040 (wq^T|wk^T|wv^T)
  unsigned short* woT = wT + 41943040;               // 16777216
  unsigned short* qkv = woT + 16777216;              // 41943040
  unsigned short* q_rot = qkv + 41943040;            // 16777216
  unsigned short* sgb = q_rot + 16777216;            // 16777216
  unsigned short* k_rot = sgb + 16777216;            // 4194304
  unsigned short* vtb = k_rot + 4194304;             // 4194304
  unsigned short* attn = wT;  // wT dead after GEMM1; reuse for attention out

  dim3 tb(32, 8);
  transpose_cvt<<<dim3(256, 128), tb, 0, stream>>>(wq, wT, 4096, 8192);
  transpose_cvt<<<dim3(32, 128), tb, 0, stream>>>(wk, wT + (size_t)8192 * 4096, 4096, 1024);
  transpose_cvt<<<dim3(32, 128), tb, 0, stream>>>(wv, wT + (size_t)9216 * 4096, 4096, 1024);
  transpose_cvt<<<dim3(128, 128), tb, 0, stream>>>(wo, woT, 4096, 4096);
  cvt_f32_bf16<<<16384, 256, 0, stream>>>(x, x_bf, 4194304);

  gemm_bt256<true><<<dim3(40, 16), 512, 0, stream>>>(x_bf, wT, (void*)qkv, 4096, 10240, 4096);
  postproc_kernel<<<40960, 256, 0, stream>>>(qkv, pos, qnw, knw, q_rot, sgb, k_rot);
  v_transpose<<<dim3(16, 2, 32), 256, 0, stream>>>(qkv, vtb);
  attn_kernel<<<2048, 256, 0, stream>>>(q_rot, k_rot, vtb, sgb, attn);
  gemm_bt256<false><<<dim3(16, 16), 512, 0, stream>>>(attn, woT, (void*)out, 4096, 4096, 4096);
}

// Round 5
// 1063.756 us; speedup vs baseline: 1.3681x; 1.3681x over previous
//
#include <hip/hip_runtime.h>
#include <cstdint>
#include <cstddef>

// ---------------------------------------------------------------------------
// Fused GQA attention block for MI355X (gfx950).
// B=4 T=1024 D=4096 N=32 Kh=8 G=4 H=128, rotary=80, theta=1e6, eps=1e-6.
// Pipeline: prep(fused transposes/cvt/sincos-LUT) -> GEMM(qkv) ->
//           post(norm/rope/gate + V transpose) -> flash attn (dbuf, causal)
//           -> GEMM(out proj).
// R6: GEMM reverted to the R4-verified 4-phase schedule (R5's 8-phase spilled:
// WRITE_SIZE 82->312 MB = scratch traffic from 96 cross-phase frag VGPRs).
// Tail changes: (1) 5 prep kernels fused into one; (2) postproc RoPE sincos
// from a double-precision-built LUT (1024x40 float2) instead of per-lane
// expf/sinf/cosf; (3) postproc+v_transpose fused; (4) attention K/V staging
// double-buffered with counted vmcnt(8) + raw s_barrier (stage(si+1) flies
// under compute(si); forced by next iteration's vmcnt; trailing barrier
// separates reads from the +2-iteration overwrite).
// MFMA layouts (guide-verified, 16x16x32 bf16):
//   A-frag: A[m=lane&15][k=(lane>>4)*8+j]
//   B-frag: B[k=(lane>>4)*8+j][n=lane&15]  (from B^T rows)
//   C/D   : row=(lane>>4)*4+r, col=lane&15
// ---------------------------------------------------------------------------

typedef __attribute__((ext_vector_type(8))) short short8;
typedef __attribute__((ext_vector_type(4))) float float4v;

__device__ __forceinline__ unsigned short f2bf(float f) {
  unsigned u = __builtin_bit_cast(unsigned, f);
  u += 0x7fffu + ((u >> 16) & 1u);            // RNE
  return (unsigned short)(u >> 16);
}
__device__ __forceinline__ float bf2f(unsigned short h) {
  unsigned u = ((unsigned)h) << 16;
  return __builtin_bit_cast(float, u);
}

// async global->LDS, 16B per lane. LDS dest is wave-uniform base + lane*16.
__device__ __forceinline__ void gload_lds16(const void* g, void* l) {
  typedef const __attribute__((address_space(1))) void as1_cv;
  typedef __attribute__((address_space(3))) void as3_v;
  __builtin_amdgcn_global_load_lds((as1_cv*)g, (as3_v*)l, 16, 0, 0);
}

// ---------------------------------------------------------------------------
// Fused prep kernel: 4 transposes (f32 -> bf16^T), x cvt, sincos LUT build.
// Grid ranges (uniform branch on blockIdx.x):
//   [0,32768)      wq  (R=4096, C=8192, nbx=256) -> wT
//   [32768,36864)  wk  (C=1024, nbx=32)          -> wT + 8192*4096
//   [36864,40960)  wv  (C=1024, nbx=32)          -> wT + 9216*4096
//   [40960,57344)  wo  (C=4096, nbx=128)         -> woT
//   [57344,73728)  x   f32->bf16 (float4/ushort4)
//   [73728,73888)  sincos table: sc[t][i] = (sin,cos)(t * 1e6^(-i/40)), f64
// ---------------------------------------------------------------------------
__device__ __forceinline__ void tcvt_body(
    const float* __restrict__ src, unsigned short* __restrict__ dst,
    int R, int C, int bx, int by, int tid, float (*tile)[33]) {
  const int tx = tid & 31, ty = tid >> 5;
  const int c0 = bx * 32, r0 = by * 32;
  for (int i = ty; i < 32; i += 8)
    tile[i][tx] = src[(size_t)(r0 + i) * C + c0 + tx];
  __syncthreads();
  for (int i = ty; i < 32; i += 8)
    dst[(size_t)(c0 + i) * R + r0 + tx] = f2bf(tile[tx][i]);
}

__global__ __launch_bounds__(256) void prep_kernel(
    const float* __restrict__ wq, const float* __restrict__ wk,
    const float* __restrict__ wv, const float* __restrict__ wo,
    const float* __restrict__ x, unsigned short* __restrict__ wT,
    unsigned short* __restrict__ woT, unsigned short* __restrict__ x_bf,
    float2* __restrict__ sctab) {
  __shared__ float tile[32][33];
  const int b = blockIdx.x, tid = threadIdx.x;
  if (b < 32768) {
    tcvt_body(wq, wT, 4096, 8192, b & 255, b >> 8, tid, tile);
  } else if (b < 36864) {
    const int r = b - 32768;
    tcvt_body(wk, wT + (size_t)8192 * 4096, 4096, 1024, r & 31, r >> 5, tid, tile);
  } else if (b < 40960) {
    const int r = b - 36864;
    tcvt_body(wv, wT + (size_t)9216 * 4096, 4096, 1024, r & 31, r >> 5, tid, tile);
  } else if (b < 57344) {
    const int r = b - 40960;
    tcvt_body(wo, woT, 4096, 4096, r & 127, r >> 7, tid, tile);
  } else if (b < 73728) {
    const int i = (b - 57344) * 256 + tid;   // < 4194304 exactly
    float4 f = ((const float4*)x)[i];
    ushort4 o;
    o.x = f2bf(f.x); o.y = f2bf(f.y); o.z = f2bf(f.z); o.w = f2bf(f.w);
    ((ushort4*)x_bf)[i] = o;
  } else {
    const int e = (b - 73728) * 256 + tid;   // < 40960 exactly
    const int t = e / 40, i = e - t * 40;
    const double ang = (double)t * exp(-0.34538776394910684 * (double)i);
    sctab[e] = make_float2((float)sin(ang), (float)cos(ang));
  }
}

// ---------------------------------------------------------------------------
// GEMM: C(M,N) = A(M,Kd) * BT(N,Kd)^T, bf16 in, f32 acc.  (R4-verified)
// 256x256 tile, BK=64, 512 threads = 8 waves (2x4), per-wave C = 128x64.
// LDS: 2 buffers x (A 256x64 + B 256x64) bf16 = 128 KiB.
// Rows are 128 B = 8 chunks of 16 B; physical chunk c holds global chunk
// c ^ (row & 7)  (both-sides rule; verified 0 bank conflicts).
// Per K-tile: 4 quadrant phases (mh,nh) = (0,0),(0,1),(1,0),(1,1):
//   q0: 16 ds_reads (af mh0, bA, bB; order pinned), lgkmcnt(4), 16 MFMA, bar
//   q1: lgkmcnt(0) [bB, aged 1 phase], 16 MFMA, bar
//   q2: 8 ds_reads (af mh1) then 8 gload_lds (tile T+1), lgkmcnt(0),
//       16 MFMA, bar
//   q3: 16 MFMA (no waits), vmcnt(0) [stage loads aged ~2 phases], bar
// ---------------------------------------------------------------------------
template <bool BF16OUT>
__global__ __launch_bounds__(512, 2) void gemm_bt256(
    const unsigned short* __restrict__ A, const unsigned short* __restrict__ BT,
    void* __restrict__ Cv, int M, int N, int Kd) {
  __shared__ unsigned short As[2][16384];   // 256 rows x 64 (bf16)
  __shared__ unsigned short Bs[2][16384];

  const int tid = threadIdx.x;
  const int lane = tid & 63;
  const int wv = tid >> 6;
  const int wr = wv >> 2, wc = wv & 3;       // 2 x 4 wave grid
  const int m0 = blockIdx.y * 256, n0 = blockIdx.x * 256;
  const int ml = lane & 15, q = lane >> 4;

  // staging addressing: slot id = r*512+tid -> row = id>>3 (0..255 across
  // halves), phys chunk = tid&7; source chunk = phys ^ (row&7); row&7 is
  // invariant across rounds/halves (64,128 = 0 mod 8).
  const int srow = tid >> 3;                 // 0..63
  const int sgc = ((tid & 7) ^ (srow & 7)) * 8;
  const unsigned short* gA = A + (size_t)(m0 + srow) * Kd + sgc;
  const unsigned short* gB = BT + (size_t)(n0 + srow) * Kd + sgc;
  const int ldst = tid * 8;                  // ushort offset, round 0

  // fragment read addressing (frag row bases are %16==0 -> row&7 == ml&7)
  const int rch = (q ^ (ml & 7)) * 8;        // ks=0 chunk; ks=1 -> offset^32
  const int aBase = (wr * 128 + ml) * 64 + rch;
  const int bBase = (wc * 64 + ml) * 64 + rch;

  float4v acc[8][4];
#pragma unroll
  for (int i = 0; i < 8; ++i)
#pragma unroll
    for (int j = 0; j < 4; ++j) acc[i][j] = (float4v)0.0f;

  const int NT = Kd >> 6;                    // K tiles of 64

  // prologue: stage tile 0 into buf 0, drain, barrier.
#pragma unroll
  for (int h = 0; h < 4; ++h) {              // halves: A0,A1,B0,B1
    const unsigned short* g = (h < 2) ? gA : gB;
    const int hr = (h & 1) * 128;
    unsigned short* l = (h < 2) ? &As[0][(h & 1) * 8192] : &Bs[0][(h & 1) * 8192];
    gload_lds16(g + (size_t)hr * Kd, l + ldst);
    gload_lds16(g + (size_t)(hr + 64) * Kd, l + ldst + 4096);
  }
  asm volatile("s_waitcnt vmcnt(0)" ::: "memory");
  __builtin_amdgcn_s_barrier();

#pragma unroll 2
  for (int T = 0; T < NT; ++T) {
    const unsigned short* Ab = As[T & 1];
    const unsigned short* Bb = Bs[T & 1];
    const bool doStage = (T + 1 < NT);

    short8 af[8], ba[4], bb[4];
    // ---- q0: issue af(mh0)+bA (12 reads), then bB (4 reads, fly) ----
#pragma unroll
    for (int i = 0; i < 4; ++i) {
      af[i * 2]     = *(const short8*)&Ab[aBase + i * 1024];
      af[i * 2 + 1] = *(const short8*)&Ab[(aBase + i * 1024) ^ 32];
    }
#pragma unroll
    for (int j = 0; j < 2; ++j) {
      ba[j * 2]     = *(const short8*)&Bb[bBase + j * 1024];
      ba[j * 2 + 1] = *(const short8*)&Bb[(bBase + j * 1024) ^ 32];
    }
    __builtin_amdgcn_sched_barrier(0);       // pin: af+bA before bB
#pragma unroll
    for (int j = 0; j < 2; ++j) {
      bb[j * 2]     = *(const short8*)&Bb[bBase + 2048 + j * 1024];
      bb[j * 2 + 1] = *(const short8*)&Bb[(bBase + 2048 + j * 1024) ^ 32];
    }
    asm volatile("s_waitcnt lgkmcnt(4)" ::: "memory");  // af+bA forced
    __builtin_amdgcn_sched_barrier(0);
    __builtin_amdgcn_s_setprio(1);
#pragma unroll
    for (int i = 0; i < 4; ++i)
#pragma unroll
      for (int j = 0; j < 2; ++j) {
        acc[i][j] = __builtin_amdgcn_mfma_f32_16x16x32_bf16(af[i * 2], ba[j * 2], acc[i][j], 0, 0, 0);
        acc[i][j] = __builtin_amdgcn_mfma_f32_16x16x32_bf16(af[i * 2 + 1], ba[j * 2 + 1], acc[i][j], 0, 0, 0);
      }
    __builtin_amdgcn_s_setprio(0);
    __builtin_amdgcn_s_barrier();

    // ---- q1: bB forced (aged 1 phase) ----
    asm volatile("s_waitcnt lgkmcnt(0)" ::: "memory");
    __builtin_amdgcn_sched_barrier(0);
    __builtin_amdgcn_s_setprio(1);
#pragma unroll
    for (int i = 0; i < 4; ++i)
#pragma unroll
      for (int j = 0; j < 2; ++j) {
        acc[i][2 + j] = __builtin_amdgcn_mfma_f32_16x16x32_bf16(af[i * 2], bb[j * 2], acc[i][2 + j], 0, 0, 0);
        acc[i][2 + j] = __builtin_amdgcn_mfma_f32_16x16x32_bf16(af[i * 2 + 1], bb[j * 2 + 1], acc[i][2 + j], 0, 0, 0);
      }
    __builtin_amdgcn_s_setprio(0);
    __builtin_amdgcn_s_barrier();

    // ---- q2: af' (mh1) reads, THEN all 8 stage loads for tile T+1 ----
#pragma unroll
    for (int i = 0; i < 4; ++i) {
      af[i * 2]     = *(const short8*)&Ab[aBase + 4096 + i * 1024];
      af[i * 2 + 1] = *(const short8*)&Ab[(aBase + 4096 + i * 1024) ^ 32];
    }
    __builtin_amdgcn_sched_barrier(0);       // pin: reads before stage issue
    if (doStage) {
      const int sb = (T + 1) & 1;
      const size_t kk = (size_t)(T + 1) * 64;
#pragma unroll
      for (int h = 0; h < 4; ++h) {
        const unsigned short* g = (h < 2) ? gA : gB;
        const int hr = (h & 1) * 128;
        unsigned short* l = (h < 2) ? &As[sb][(h & 1) * 8192] : &Bs[sb][(h & 1) * 8192];
        gload_lds16(g + (size_t)hr * Kd + kk, l + ldst);
        gload_lds16(g + (size_t)(hr + 64) * Kd + kk, l + ldst + 4096);
      }
    }
    asm volatile("s_waitcnt lgkmcnt(0)" ::: "memory");  // af'
    __builtin_amdgcn_sched_barrier(0);
    __builtin_amdgcn_s_setprio(1);
#pragma unroll
    for (int i = 0; i < 4; ++i)
#pragma unroll
      for (int j = 0; j < 2; ++j) {
        acc[4 + i][j] = __builtin_amdgcn_mfma_f32_16x16x32_bf16(af[i * 2], ba[j * 2], acc[4 + i][j], 0, 0, 0);
        acc[4 + i][j] = __builtin_amdgcn_mfma_f32_16x16x32_bf16(af[i * 2 + 1], ba[j * 2 + 1], acc[4 + i][j], 0, 0, 0);
      }
    __builtin_amdgcn_s_setprio(0);
    __builtin_amdgcn_s_barrier();

    // ---- q3: pure MFMA (af', bB already forced); boundary ----
    __builtin_amdgcn_s_setprio(1);
#pragma unroll
    for (int i = 0; i < 4; ++i)
#pragma unroll
      for (int j = 0; j < 2; ++j) {
        acc[4 + i][2 + j] = __builtin_amdgcn_mfma_f32_16x16x32_bf16(af[i * 2], bb[j * 2], acc[4 + i][2 + j], 0, 0, 0);
        acc[4 + i][2 + j] = __builtin_amdgcn_mfma_f32_16x16x32_bf16(af[i * 2 + 1], bb[j * 2 + 1], acc[4 + i][2 + j], 0, 0, 0);
      }
    __builtin_amdgcn_s_setprio(0);
    if (doStage)
      asm volatile("s_waitcnt vmcnt(0)" ::: "memory");  // aged ~2 phases
    __builtin_amdgcn_s_barrier();
  }

  // epilogue (acc[i][j]: rows wr*128+i*16+q*4, cols wc*64+j*16+ml)
#pragma unroll
  for (int i = 0; i < 8; ++i) {
#pragma unroll
    for (int j = 0; j < 4; ++j) {
      const int grow = m0 + wr * 128 + i * 16 + q * 4;
      const int gcol = n0 + wc * 64 + j * 16 + ml;
#pragma unroll
      for (int r = 0; r < 4; ++r) {
        size_t idx = (size_t)(grow + r) * N + gcol;
        if constexpr (BF16OUT)
          ((unsigned short*)Cv)[idx] = f2bf(acc[i][j][r]);
        else
          ((float*)Cv)[idx] = acc[i][j][r];
      }
    }
  }
}

// ---------------------------------------------------------------------------
// Fused post kernel:
//   blocks [0,40960): postproc q/gate/k — one wave per (row m, slot hs<40):
//     hs<32 : q head hs -> rmsnorm, rope (LUT) -> q_rot; gate -> sigmoid
//     hs>=32: k head    -> rmsnorm, rope (LUT) -> k_rot (layout (b,kh,t,h))
//   blocks [40960,41984): V 64x64 bf16 transpose -> vt (b,kh,h,t)
// ---------------------------------------------------------------------------
__global__ __launch_bounds__(256) void post_kernel(
    const unsigned short* __restrict__ qkv, const int* __restrict__ positions,
    const float* __restrict__ qnw, const float* __restrict__ knw,
    unsigned short* __restrict__ q_rot, unsigned short* __restrict__ sgb,
    unsigned short* __restrict__ k_rot, unsigned short* __restrict__ vtb,
    const float2* __restrict__ sctab) {
  __shared__ unsigned short vt_tile[64][65];
  const int bidx = blockIdx.x;

  if (bidx < 40960) {
    const int wave = threadIdx.x >> 6, lane = threadIdx.x & 63;
    const int gslot = bidx * 4 + wave;
    const int m = gslot / 40, hs = gslot % 40;
    const int b = m >> 10, t = m & 1023;

    const unsigned short* base = (hs < 32)
        ? qkv + (size_t)m * 10240 + hs * 256
        : qkv + (size_t)m * 10240 + 8192 + (hs - 32) * 128;

    float v1 = bf2f(base[lane]);        // h = lane
    float v2 = bf2f(base[64 + lane]);   // h = lane + 64

    // RMS norm over 128
    float ss = v1 * v1 + v2 * v2;
    for (int off = 32; off > 0; off >>= 1) ss += __shfl_xor(ss, off);
    const float r = rsqrtf(ss * (1.0f / 128.0f) + 1e-6f);
    const float* nw = (hs < 32) ? qnw : knw;
    v1 *= r * (1.0f + nw[lane]);
    v2 *= r * (1.0f + nw[64 + lane]);

    // RoPE via LUT: pair (i, i+40), i in 0..39. sc[t][i] = (sin,cos).
    const float2* sc = sctab + (size_t)positions[m] * 40;
    const int i1 = (lane < 40) ? lane : lane - 40;
    const float2 sc1 = sc[i1];
    const float2 sc2 = sc[(lane < 16) ? (lane + 24) : 0];
    const float s1 = sc1.x, c1 = sc1.y;
    const float s2 = sc2.x, c2 = sc2.y;

    const float shA1 = __shfl(v1, (lane + 40) & 63);
    const float shA2 = __shfl(v2, (lane + 40) & 63);
    const float shX = __shfl(v1, (lane + 24) & 63);
    const float pA = (lane < 24) ? shA1 : shA2;  // x[lane+40]
    const float o1 = (lane < 40) ? (v1 * c1 - pA * s1) : (v1 * c1 + shX * s1);
    const float o2 = (lane < 16) ? (v2 * c2 + shX * s2) : v2;

    if (hs < 32) {
      size_t qb = ((size_t)m * 32 + hs) * 128;
      q_rot[qb + lane] = f2bf(o1);
      q_rot[qb + 64 + lane] = f2bf(o2);
      float g1 = bf2f(base[128 + lane]), g2 = bf2f(base[192 + lane]);
      sgb[qb + lane] = f2bf(1.0f / (1.0f + expf(-g1)));
      sgb[qb + 64 + lane] = f2bf(1.0f / (1.0f + expf(-g2)));
    } else {
      const int kh = hs - 32;
      size_t kb = ((size_t)(b * 8 + kh) * 1024 + t) * 128;
      k_rot[kb + lane] = f2bf(o1);
      k_rot[kb + 64 + lane] = f2bf(o2);
    }
  } else {
    // V transpose: rel = tt (16) | hh (2) | bk (32)
    const int rel = bidx - 40960;
    const int tt = rel & 15, hh = (rel >> 4) & 1, bk = rel >> 5;
    const int t0 = tt * 64, h0 = hh * 64;
    const int b = bk >> 3, kh = bk & 7;
    const int tx = threadIdx.x & 63, ty = threadIdx.x >> 6;
    const unsigned short* src =
        qkv + (size_t)(b * 1024 + t0) * 10240 + 9216 + kh * 128 + h0;
    for (int i = ty; i < 64; i += 4)
      vt_tile[i][tx] = src[(size_t)i * 10240 + tx];
    __syncthreads();
    unsigned short* dst = vtb + ((size_t)bk * 128 + h0) * 1024 + t0;
    for (int i = ty; i < 64; i += 4)
      dst[(size_t)i * 1024 + tx] = vt_tile[tx][i];
  }
}

// ---------------------------------------------------------------------------
// Flash attention. Block = (b, n, 64-row Q tile). 4 waves x 16 q-rows.
// R6: double-buffered K/V staging. Per iter: issue stage(si+1) -> counted
// vmcnt(8) (forces stage(si), FIFO: the 8 newest are si+1's) -> barrier ->
// compute(buf si&1) -> barrier (protects buf from the si+2 overwrite).
// Last iter drains vmcnt(0). Ks/Vts XOR-swizzled; Ps padded to stride 72.
// LDS = 32K + 32K + 9.2K = 73 KB (2 blocks/CU).
// ---------------------------------------------------------------------------
__global__ __launch_bounds__(256) void attn_kernel(
    const unsigned short* __restrict__ q_rot, const unsigned short* __restrict__ k_rot,
    const unsigned short* __restrict__ vt, const unsigned short* __restrict__ sgate,
    unsigned short* __restrict__ attn_out) {
  __shared__ unsigned short Ks[2][64 * 128];   // 16 chunks/row, swizzle mask 15
  __shared__ unsigned short Vts[2][128 * 64];  // 8 chunks/row, swizzle mask 7
  __shared__ unsigned short Ps[64 * 72];       // padded, plain stores

  const int tid = threadIdx.x;
  const int lane = tid & 63, w = tid >> 6;
  const int qt = blockIdx.x & 15;
  const int n = (blockIdx.x >> 4) & 31;
  const int b = blockIdx.x >> 9;
  const int kh = n >> 2;
  const int t0 = qt * 64;
  const int ml = lane & 15, q = lane >> 4;
  const float SCALE = 0.08838834764831845f;  // H^-0.5

  short8 aq[4];
  {
    const unsigned short* qp =
        q_rot + (((size_t)(b * 1024 + t0 + w * 16 + ml)) * 32 + n) * 128 + q * 8;
#pragma unroll
    for (int ks = 0; ks < 4; ++ks) aq[ks] = *(const short8*)(qp + ks * 32);
  }

  float4v O[8];
#pragma unroll
  for (int i = 0; i < 8; ++i) O[i] = (float4v)0.0f;
  float mrow[4] = {-3e38f, -3e38f, -3e38f, -3e38f};
  float lrow[4] = {0.f, 0.f, 0.f, 0.f};

  const unsigned short* kbase = k_rot + (size_t)(b * 8 + kh) * 1024 * 128;
  const unsigned short* vbase = vt + (size_t)(b * 8 + kh) * 128 * 1024;
  const int rK = tid >> 4, cK = tid & 15;  // K stage: 64 rows x 16 chunks
  const int cKsw = (cK ^ rK) * 8;          // rK&15 == rK
  const int rV = tid >> 3, cV = tid & 7;   // V stage: 128 rows x 8 chunks
  const int cVsw = (cV ^ (rV & 7)) * 8;

#define ATTN_STAGE(SI, BF) do {                                               \
    const int ss0 = (SI) * 64;                                                \
    _Pragma("unroll")                                                         \
    for (int it = 0; it < 4; ++it) {                                          \
      const int li = it * 256 + tid;                                          \
      gload_lds16(kbase + (size_t)(ss0 + rK + it * 16) * 128 + cKsw,          \
                  &Ks[BF][li * 8]);                                           \
      gload_lds16(vbase + (size_t)(rV + it * 32) * 1024 + ss0 + cVsw,         \
                  &Vts[BF][li * 8]);                                          \
    } } while (0)

  ATTN_STAGE(0, 0);

  for (int si = 0; si <= qt; ++si) {
    const int buf = si & 1;
    const int s0 = si * 64;
    if (si < qt) {
      ATTN_STAGE(si + 1, buf ^ 1);
      __builtin_amdgcn_sched_barrier(0);
      asm volatile("s_waitcnt vmcnt(8)" ::: "memory");   // forces stage(si)
    } else {
      asm volatile("s_waitcnt vmcnt(0)" ::: "memory");
    }
    __builtin_amdgcn_s_barrier();
    __builtin_amdgcn_sched_barrier(0);

    // S = Q K^T
    float4v Sv[4];
#pragma unroll
    for (int j = 0; j < 4; ++j) Sv[j] = (float4v)0.0f;
#pragma unroll
    for (int ks = 0; ks < 4; ++ks) {
#pragma unroll
      for (int j = 0; j < 4; ++j) {
        short8 bk = *(const short8*)&Ks[buf][(j * 16 + ml) * 128 + (((ks * 4 + q) ^ ml) * 8)];
        Sv[j] = __builtin_amdgcn_mfma_f32_16x16x32_bf16(aq[ks], bk, Sv[j], 0, 0, 0);
      }
    }

    // scale + causal mask + online softmax (rows: t = t0+w*16+q*4+rr)
    float P[4][4];
#pragma unroll
    for (int rr = 0; rr < 4; ++rr) {
      const int tg = t0 + w * 16 + q * 4 + rr;
      float vmax = -3e38f;
#pragma unroll
      for (int j = 0; j < 4; ++j) {
        const int sj = s0 + j * 16 + ml;
        float v = Sv[j][rr] * SCALE;
        if (sj > tg) v = -3.0e38f;
        P[j][rr] = v;
        vmax = fmaxf(vmax, v);
      }
      for (int off = 1; off < 16; off <<= 1) vmax = fmaxf(vmax, __shfl_xor(vmax, off));
      const float mnew = fmaxf(mrow[rr], vmax);
      const float alpha = __expf(mrow[rr] - mnew);
      mrow[rr] = mnew;
      lrow[rr] *= alpha;
#pragma unroll
      for (int ht = 0; ht < 8; ++ht) O[ht][rr] *= alpha;
      float rsum = 0.f;
#pragma unroll
      for (int j = 0; j < 4; ++j) {
        float e = __expf(P[j][rr] - mnew);
        P[j][rr] = e;
        rsum += e;
      }
      for (int off = 1; off < 16; off <<= 1) rsum += __shfl_xor(rsum, off);
      lrow[rr] += rsum;
    }

    // P: C-layout regs -> LDS [t][s] (padded stride 72)
#pragma unroll
    for (int rr = 0; rr < 4; ++rr)
#pragma unroll
      for (int j = 0; j < 4; ++j)
        Ps[(w * 16 + q * 4 + rr) * 72 + j * 16 + ml] = f2bf(P[j][rr]);

    // O += P V
#pragma unroll
    for (int ks = 0; ks < 2; ++ks) {
      short8 ap = *(const short8*)&Ps[(w * 16 + ml) * 72 + ks * 32 + q * 8];
#pragma unroll
      for (int ht = 0; ht < 8; ++ht) {
        short8 bv = *(const short8*)&Vts[buf][(ht * 16 + ml) * 64 + (((ks * 4 + q) ^ (ml & 7)) * 8)];
        O[ht] = __builtin_amdgcn_mfma_f32_16x16x32_bf16(ap, bv, O[ht], 0, 0, 0);
      }
    }
    __builtin_amdgcn_sched_barrier(0);
    __builtin_amdgcn_s_barrier();
  }
#undef ATTN_STAGE

  // epilogue: normalize, gate, store bf16 (M, N*H)
#pragma unroll
  for (int rr = 0; rr < 4; ++rr) {
    const int tg = t0 + w * 16 + q * 4 + rr;
    const size_t ob = ((size_t)(b * 1024 + tg) * 32 + n) * 128;
    const float inv = 1.0f / lrow[rr];
#pragma unroll
    for (int ht = 0; ht < 8; ++ht) {
      const int h = ht * 16 + ml;
      attn_out[ob + h] = f2bf(O[ht][rr] * inv * bf2f(sgate[ob + h]));
    }
  }
}

// ---------------------------------------------------------------------------
extern "C" void kernel_launch(void* const* d_in, const int* in_sizes, int n_in,
                              void* d_out, int out_size, void* d_ws, size_t ws_size,
                              hipStream_t stream) {
  (void)in_sizes; (void)n_in; (void)out_size; (void)ws_size;
  const float* x = (const float*)d_in[0];
  const int* pos = (const int*)d_in[1];
  const float* wq = (const float*)d_in[2];
  const float* wk = (const float*)d_in[3];
  const float* wv = (const float*)d_in[4];
  const float* wo = (const float*)d_in[5];
  const float* qnw = (const float*)d_in[6];
  const float* knw = (const float*)d_in[7];
  float* out = (float*)d_out;

  unsigned short* ws = (unsigned short*)d_ws;
  unsigned short* x_bf = ws;                         // 16777216
  unsigned short* wT = x_bf + 16777216;              // 41943040 (wq^T|wk^T|wv^T)
  unsigned short* woT = wT + 41943040;               // 16777216
  unsigned short* qkv = woT + 16777216;              // 41943040
  unsigned short* q_rot = qkv + 41943040;            // 16777216
  unsigned short* sgb = q_rot + 16777216;            // 16777216
  unsigned short* k_rot = sgb + 16777216;            // 4194304
  unsigned short* vtb = k_rot + 4194304;             // 4194304
  float2* sctab = (float2*)(vtb + 4194304);          // 40960 float2 (328 KB)
  unsigned short* attn = wT;  // wT dead after GEMM1; reuse for attention out

  prep_kernel<<<73888, 256, 0, stream>>>(wq, wk, wv, wo, x, wT, woT, x_bf, sctab);
  gemm_bt256<true><<<dim3(40, 16), 512, 0, stream>>>(x_bf, wT, (void*)qkv, 4096, 10240, 4096);
  post_kernel<<<41984, 256, 0, stream>>>(qkv, pos, qnw, knw, q_rot, sgb, k_rot, vtb, sctab);
  attn_kernel<<<2048, 256, 0, stream>>>(q_rot, k_rot, vtb, sgb, attn);
  gemm_bt256<false><<<dim3(16, 16), 512, 0, stream>>>(attn, woT, (void*)out, 4096, 4096, 4096);
}